// Round 7
// baseline (464.165 us; speedup 1.0000x reference)
//
#include <hip/hip_runtime.h>
#include <cstdint>

#define N_NODES 50000
#define N_EDGES 800000
#define DIM 64
#define HIDDEN 256

#define BSHIFT 6
#define BNODES 64                                   // nodes per bucket
#define NBUCK ((N_NODES + BNODES - 1) / BNODES)     // 782
#define EPB 4096                                    // edges per partition block
#define PBLKS ((N_EDGES + EPB - 1) / EPB)           // 196

typedef __attribute__((ext_vector_type(8))) short bf16x8;
typedef __attribute__((ext_vector_type(4))) float f32x4;

__device__ __forceinline__ unsigned short bf16_rne(float f) {
    union { float f; uint32_t u; } cv; cv.f = f;
    uint32_t u = cv.u;
    u += 0x7FFFu + ((u >> 16) & 1u);
    return (unsigned short)(u >> 16);
}

__device__ __forceinline__ float bf2f(unsigned short us) {
    union { uint32_t u; float f; } cv; cv.u = ((uint32_t)us) << 16;
    return cv.f;
}

// ---------------------------------------------------------------------------
// Prep: bf16 conversions. xb h-half from h; w1t[n][k] (256x128); w2t[d][j] (64x256).
// ---------------------------------------------------------------------------
#define PREP_TOTAL (N_NODES * DIM + 128 * 256 + 256 * 64)
__global__ __launch_bounds__(256)
void prep_kernel(const float* __restrict__ h, const float* __restrict__ W1,
                 const float* __restrict__ W2, unsigned short* __restrict__ xb,
                 unsigned short* __restrict__ w1t, unsigned short* __restrict__ w2t) {
    int i = blockIdx.x * 256 + threadIdx.x;
    if (i < N_NODES * DIM) {
        int node = i >> 6, d = i & 63;
        xb[node * 128 + d] = bf16_rne(h[i]);
    } else if (i < N_NODES * DIM + 128 * 256) {
        int j = i - N_NODES * DIM;
        int k = j >> 8, n = j & 255;          // W1[k][n]
        w1t[n * 128 + k] = bf16_rne(W1[j]);
    } else if (i < PREP_TOTAL) {
        int j = i - N_NODES * DIM - 128 * 256;
        int jr = j >> 6, d = j & 63;          // W2[j][d]
        w2t[d * 256 + jr] = bf16_rne(W2[j]);
    }
}

// ---------------------------------------------------------------------------
// Bucket histogram: LDS bins, one global atomic per non-empty bin per block.
// ---------------------------------------------------------------------------
__global__ __launch_bounds__(256)
void bhist_kernel(const int* __restrict__ dst, int* __restrict__ gcnt) {
    __shared__ int lcnt[NBUCK];
    const int t = threadIdx.x;
    for (int i = t; i < NBUCK; i += 256) lcnt[i] = 0;
    __syncthreads();
    const int base = blockIdx.x * EPB;
    #pragma unroll
    for (int i = 0; i < EPB / 256; ++i) {
        int e = base + t + i * 256;
        if (e < N_EDGES) atomicAdd(&lcnt[dst[e] >> BSHIFT], 1);
    }
    __syncthreads();
    for (int i = t; i < NBUCK; i += 256) {
        int c = lcnt[i];
        if (c) atomicAdd(&gcnt[i], c);
    }
}

// ---------------------------------------------------------------------------
// Scan of NBUCK bucket counts -> bstart (exclusive) + gwptr cursors. 1 block.
// 4 buckets per thread.
// ---------------------------------------------------------------------------
__global__ __launch_bounds__(256)
void bscan_kernel(const int* __restrict__ gcnt, int* __restrict__ bstart,
                  int* __restrict__ gwptr) {
    __shared__ int ws[4];
    const int t = threadIdx.x;
    const int base = t * 4;
    int c0 = (base     < NBUCK) ? gcnt[base]     : 0;
    int c1 = (base + 1 < NBUCK) ? gcnt[base + 1] : 0;
    int c2 = (base + 2 < NBUCK) ? gcnt[base + 2] : 0;
    int c3 = (base + 3 < NBUCK) ? gcnt[base + 3] : 0;
    const int s = c0 + c1 + c2 + c3;
    int inc = s;
    const int lane = t & 63;
    #pragma unroll
    for (int off = 1; off < 64; off <<= 1) {
        int u = __shfl_up(inc, off, 64);
        if (lane >= off) inc += u;
    }
    if (lane == 63) ws[t >> 6] = inc;
    __syncthreads();
    const int w = t >> 6;
    int woff = 0;
    if (w > 0) woff += ws[0];
    if (w > 1) woff += ws[1];
    if (w > 2) woff += ws[2];
    int ex = woff + (inc - s);
    const int p0 = ex, p1 = ex + c0, p2 = p1 + c1, p3 = p2 + c2;
    if (base     < NBUCK) { bstart[base]     = p0; gwptr[base]     = p0; }
    if (base + 1 < NBUCK) { bstart[base + 1] = p1; gwptr[base + 1] = p1; }
    if (base + 2 < NBUCK) { bstart[base + 2] = p2; gwptr[base + 2] = p2; }
    if (base + 3 < NBUCK) { bstart[base + 3] = p3; gwptr[base + 3] = p3; }
    if (t == 255) bstart[NBUCK] = N_EDGES;
}

// ---------------------------------------------------------------------------
// Partition: bin EPB edges into LDS by bucket, flush contiguous runs.
// Packed edge: (dst & 63) << 16 | src   (src < 50000 < 2^16)
// ---------------------------------------------------------------------------
__global__ __launch_bounds__(256)
void part_kernel(const int* __restrict__ src, const int* __restrict__ dst,
                 int* __restrict__ gwptr, unsigned int* __restrict__ gbuf) {
    __shared__ unsigned int pairs[EPB];       // 16 KB
    __shared__ int cntA[NBUCK];
    __shared__ int offs[NBUCK];
    __shared__ int wc[NBUCK];
    __shared__ int ws[4];

    const int t = threadIdx.x;
    for (int i = t; i < NBUCK; i += 256) cntA[i] = 0;
    __syncthreads();

    const int base = blockIdx.x * EPB;
    unsigned int epack[EPB / 256];
    int ebuck[EPB / 256];
    #pragma unroll
    for (int i = 0; i < EPB / 256; ++i) {
        int e = base + t + i * 256;
        if (e < N_EDGES) {
            int s_ = src[e], d_ = dst[e];
            int b = d_ >> BSHIFT;
            epack[i] = ((unsigned)(d_ & (BNODES - 1)) << 16) | (unsigned)s_;
            ebuck[i] = b;
            atomicAdd(&cntA[b], 1);
        } else {
            ebuck[i] = -1;
        }
    }
    __syncthreads();

    // exclusive scan of cntA (4 buckets/thread)
    const int sb = t * 4;
    int c0 = (sb     < NBUCK) ? cntA[sb]     : 0;
    int c1 = (sb + 1 < NBUCK) ? cntA[sb + 1] : 0;
    int c2 = (sb + 2 < NBUCK) ? cntA[sb + 2] : 0;
    int c3 = (sb + 3 < NBUCK) ? cntA[sb + 3] : 0;
    const int s = c0 + c1 + c2 + c3;
    int inc = s;
    const int lane = t & 63;
    #pragma unroll
    for (int off = 1; off < 64; off <<= 1) {
        int u = __shfl_up(inc, off, 64);
        if (lane >= off) inc += u;
    }
    if (lane == 63) ws[t >> 6] = inc;
    __syncthreads();
    const int w = t >> 6;
    int woff = 0;
    if (w > 0) woff += ws[0];
    if (w > 1) woff += ws[1];
    if (w > 2) woff += ws[2];
    int ex = woff + (inc - s);
    const int p0 = ex, p1 = ex + c0, p2 = p1 + c1, p3 = p2 + c2;
    if (sb     < NBUCK) { offs[sb]     = p0; wc[sb]     = p0; }
    if (sb + 1 < NBUCK) { offs[sb + 1] = p1; wc[sb + 1] = p1; }
    if (sb + 2 < NBUCK) { offs[sb + 2] = p2; wc[sb + 2] = p2; }
    if (sb + 3 < NBUCK) { offs[sb + 3] = p3; wc[sb + 3] = p3; }
    __syncthreads();

    // place into LDS pairs
    #pragma unroll
    for (int i = 0; i < EPB / 256; ++i) {
        if (ebuck[i] >= 0) {
            int p = atomicAdd(&wc[ebuck[i]], 1);
            pairs[p] = epack[i];
        }
    }
    __syncthreads();

    // flush contiguous runs per bucket
    for (int b = t; b < NBUCK; b += 256) {
        int c = cntA[b];
        if (c) {
            int gb = atomicAdd(&gwptr[b], c);
            int o = offs[b];
            for (int i = 0; i < c; ++i) gbuf[gb + i] = pairs[o + i];
        }
    }
}

// ---------------------------------------------------------------------------
// Aggregate: block per bucket. fp32 LDS accumulators, LDS atomics, coalesced
// xb row reads (128B/edge), coalesced bf16 output rows.
// ---------------------------------------------------------------------------
__global__ __launch_bounds__(256)
void agg_kernel(const int* __restrict__ bstart, const unsigned int* __restrict__ gbuf,
                unsigned short* __restrict__ xb) {
    __shared__ float sacc[BNODES][DIM];   // 16 KB
    __shared__ float sdeg[BNODES];

    const int t = threadIdx.x;
    const int b = blockIdx.x;
    for (int i = t; i < BNODES * DIM; i += 256) ((float*)sacc)[i] = 0.f;
    for (int i = t; i < BNODES; i += 256) sdeg[i] = 0.f;
    __syncthreads();

    const int lane = t & 63;
    const int w = t >> 6;
    const int s0 = bstart[b], s1 = bstart[b + 1];

    for (int eb = s0 + w * 64; eb < s1; eb += 256) {
        int n = s1 - eb; if (n > 64) n = 64;
        int mypair = (lane < n) ? (int)gbuf[eb + lane] : 0;
        if (n == 64) {
            #pragma unroll 16
            for (int i = 0; i < 64; ++i) {
                int pr = __shfl(mypair, i, 64);
                int srcn = pr & 0xFFFF;
                int dl = (pr >> 16) & (BNODES - 1);
                float v = bf2f(xb[(size_t)srcn * 128 + lane]);
                atomicAdd(&sacc[dl][lane], v);
                if (lane == 0) atomicAdd(&sdeg[dl], 1.0f);
            }
        } else {
            for (int i = 0; i < n; ++i) {
                int pr = __shfl(mypair, i, 64);
                int srcn = pr & 0xFFFF;
                int dl = (pr >> 16) & (BNODES - 1);
                float v = bf2f(xb[(size_t)srcn * 128 + lane]);
                atomicAdd(&sacc[dl][lane], v);
                if (lane == 0) atomicAdd(&sdeg[dl], 1.0f);
            }
        }
    }
    __syncthreads();

    // write mean (or copy h-half) into agg-half of xb
    const int node0 = b * BNODES;
    for (int n = w; n < BNODES; n += 4) {
        int node = node0 + n;
        if (node >= N_NODES) break;
        float dg = sdeg[n];
        unsigned short res;
        if (dg > 0.f) res = bf16_rne(sacc[n][lane] / dg);
        else          res = xb[(size_t)node * 128 + lane];
        xb[(size_t)node * 128 + 64 + lane] = res;
    }
}

// ---------------------------------------------------------------------------
// MFMA MLP: block = 64 nodes, 4 waves. (unchanged from round 6)
// ---------------------------------------------------------------------------
__global__ __launch_bounds__(256)
void mlp_mfma_kernel(const unsigned short* __restrict__ xb,
                     const unsigned short* __restrict__ w1t,
                     const unsigned short* __restrict__ w2t,
                     const float* __restrict__ b1v,
                     const float* __restrict__ b2v,
                     float* __restrict__ out) {
    __shared__ unsigned short hid[64][264];

    const int tid = threadIdx.x;
    const int w   = tid >> 6;
    const int l   = tid & 63;
    const int l15 = l & 15;
    const int kg  = l >> 4;                 // 0..3
    const int node0 = blockIdx.x * 64;

    int arow[4];
    #pragma unroll
    for (int nt = 0; nt < 4; ++nt) {
        int r = node0 + nt * 16 + l15;
        arow[nt] = (r < N_NODES) ? r : (N_NODES - 1);
    }

    // ---- layer 1 ----
    f32x4 acc[4][4];   // [node-tile][j-tile]
    #pragma unroll
    for (int a = 0; a < 4; ++a)
        #pragma unroll
        for (int b = 0; b < 4; ++b) acc[a][b] = f32x4{0.f, 0.f, 0.f, 0.f};

    #pragma unroll
    for (int s = 0; s < 4; ++s) {
        const int kofs = s * 32 + kg * 8;
        bf16x8 a[4], b[4];
        #pragma unroll
        for (int nt = 0; nt < 4; ++nt)
            a[nt] = *(const bf16x8*)(xb + (size_t)arow[nt] * 128 + kofs);
        #pragma unroll
        for (int jt = 0; jt < 4; ++jt)
            b[jt] = *(const bf16x8*)(w1t + ((w * 4 + jt) * 16 + l15) * 128 + kofs);
        #pragma unroll
        for (int nt = 0; nt < 4; ++nt)
            #pragma unroll
            for (int jt = 0; jt < 4; ++jt)
                acc[nt][jt] = __builtin_amdgcn_mfma_f32_16x16x32_bf16(
                    a[nt], b[jt], acc[nt][jt], 0, 0, 0);
    }

    // ---- bias + exact GELU -> hid LDS ----
    #pragma unroll
    for (int jt = 0; jt < 4; ++jt) {
        const int jcol = (w * 4 + jt) * 16 + l15;
        float bias = b1v[jcol];
        #pragma unroll
        for (int nt = 0; nt < 4; ++nt) {
            #pragma unroll
            for (int r = 0; r < 4; ++r) {
                float v = acc[nt][jt][r] + bias;
                float g = 0.5f * v * (1.0f + erff(v * 0.70710678118654752440f));
                hid[nt * 16 + kg * 4 + r][jcol] = bf16_rne(g);
            }
        }
    }
    __syncthreads();

    // ---- layer 2: wave w -> d-tile w ----
    f32x4 acc2[4];
    #pragma unroll
    for (int a = 0; a < 4; ++a) acc2[a] = f32x4{0.f, 0.f, 0.f, 0.f};

    #pragma unroll
    for (int s = 0; s < 8; ++s) {
        const int kofs = s * 32 + kg * 8;
        bf16x8 bb = *(const bf16x8*)(w2t + (w * 16 + l15) * 256 + kofs);
        #pragma unroll
        for (int nt = 0; nt < 4; ++nt) {
            bf16x8 aa = *(const bf16x8*)&hid[nt * 16 + l15][kofs];
            acc2[nt] = __builtin_amdgcn_mfma_f32_16x16x32_bf16(aa, bb, acc2[nt], 0, 0, 0);
        }
    }

    float bias2 = b2v[w * 16 + l15];
    #pragma unroll
    for (int nt = 0; nt < 4; ++nt) {
        #pragma unroll
        for (int r = 0; r < 4; ++r) {
            int node = node0 + nt * 16 + kg * 4 + r;
            if (node < N_NODES)
                out[(size_t)node * DIM + w * 16 + l15] = acc2[nt][r] + bias2;
        }
    }
}

// ---------------------------------------------------------------------------
extern "C" void kernel_launch(void* const* d_in, const int* in_sizes, int n_in,
                              void* d_out, int out_size, void* d_ws, size_t ws_size,
                              hipStream_t stream) {
    const float* h  = (const float*)d_in[0];
    const int* eidx = (const int*)d_in[1];   // [2, N_EDGES]: src row then dst row
    const float* W1 = (const float*)d_in[2];
    const float* b1 = (const float*)d_in[3];
    const float* W2 = (const float*)d_in[4];
    const float* b2 = (const float*)d_in[5];
    float* out = (float*)d_out;

    const int* src = eidx;
    const int* dst = eidx + N_EDGES;

    // workspace layout
    unsigned short* xb  = (unsigned short*)d_ws;          // 6,400,000 ushort
    unsigned short* w1t = xb + (size_t)N_NODES * 128;     // 32,768
    unsigned short* w2t = w1t + 128 * 256;                // 16,384
    unsigned int* gbuf  = (unsigned int*)(w2t + 256 * 64);// 800,000 uint32
    int* gcnt   = (int*)(gbuf + N_EDGES);                 // NBUCK
    int* bstart = gcnt + NBUCK;                           // NBUCK+1
    int* gwptr  = bstart + NBUCK + 1;                     // NBUCK

    hipMemsetAsync(gcnt, 0, (size_t)NBUCK * sizeof(int), stream);

    prep_kernel<<<(PREP_TOTAL + 255) / 256, 256, 0, stream>>>(h, W1, W2, xb, w1t, w2t);
    bhist_kernel<<<PBLKS, 256, 0, stream>>>(dst, gcnt);
    bscan_kernel<<<1, 256, 0, stream>>>(gcnt, bstart, gwptr);
    part_kernel<<<PBLKS, 256, 0, stream>>>(src, dst, gwptr, gbuf);
    agg_kernel<<<NBUCK, 256, 0, stream>>>(bstart, gbuf, xb);
    {
        int grid = (N_NODES + 63) / 64;
        mlp_mfma_kernel<<<grid, 256, 0, stream>>>(xb, w1t, w2t, b1, b2, out);
    }
}

// Round 8
// 302.527 us; speedup vs baseline: 1.5343x; 1.5343x over previous
//
#include <hip/hip_runtime.h>
#include <cstdint>

#define N_NODES 50000
#define N_EDGES 800000
#define DIM 64
#define HIDDEN 256

#define NCB 196                                  // coarse buckets (dst >> 8)
#define EPA 4096                                 // edges per partA/chist block
#define ABLKS ((N_EDGES + EPA - 1) / EPA)        // 196
#define MAXBE 5120                               // max edges per coarse bucket (mean 4081, +16 sigma)

typedef __attribute__((ext_vector_type(8))) short bf16x8;
typedef __attribute__((ext_vector_type(4))) float f32x4;

__device__ __forceinline__ unsigned short bf16_rne(float f) {
    union { float f; uint32_t u; } cv; cv.f = f;
    uint32_t u = cv.u;
    u += 0x7FFFu + ((u >> 16) & 1u);
    return (unsigned short)(u >> 16);
}

__device__ __forceinline__ float bf2f(unsigned short us) {
    union { uint32_t u; float f; } cv; cv.u = ((uint32_t)us) << 16;
    return cv.f;
}

// ---------------------------------------------------------------------------
// Prep: bf16 conversions. xb h-half from h; w1t[n][k] (256x128); w2t[d][j] (64x256).
// ---------------------------------------------------------------------------
#define PREP_TOTAL (N_NODES * DIM + 128 * 256 + 256 * 64)
__global__ __launch_bounds__(256)
void prep_kernel(const float* __restrict__ h, const float* __restrict__ W1,
                 const float* __restrict__ W2, unsigned short* __restrict__ xb,
                 unsigned short* __restrict__ w1t, unsigned short* __restrict__ w2t) {
    int i = blockIdx.x * 256 + threadIdx.x;
    if (i < N_NODES * DIM) {
        int node = i >> 6, d = i & 63;
        xb[node * 128 + d] = bf16_rne(h[i]);
    } else if (i < N_NODES * DIM + 128 * 256) {
        int j = i - N_NODES * DIM;
        int k = j >> 8, n = j & 255;          // W1[k][n]
        w1t[n * 128 + k] = bf16_rne(W1[j]);
    } else if (i < PREP_TOTAL) {
        int j = i - N_NODES * DIM - 128 * 256;
        int jr = j >> 6, d = j & 63;          // W2[j][d]
        w2t[d * 256 + jr] = bf16_rne(W2[j]);
    }
}

// ---------------------------------------------------------------------------
// Coarse histogram over dst>>8: LDS bins, <=196 global atomics per block.
// ---------------------------------------------------------------------------
__global__ __launch_bounds__(256)
void chist_kernel(const int* __restrict__ dst, int* __restrict__ gcnt) {
    __shared__ int lc[NCB];
    const int t = threadIdx.x;
    for (int i = t; i < NCB; i += 256) lc[i] = 0;
    __syncthreads();
    const int base = blockIdx.x * EPA;
    #pragma unroll
    for (int i = 0; i < EPA / 256; ++i) {
        int e = base + t + i * 256;
        if (e < N_EDGES) atomicAdd(&lc[((unsigned)dst[e]) >> 8], 1);
    }
    __syncthreads();
    for (int i = t; i < NCB; i += 256) {
        int c = lc[i];
        if (c) atomicAdd(&gcnt[i], c);
    }
}

// ---------------------------------------------------------------------------
// Scan of NCB coarse counts -> cstart (exclusive) + gwptr. Single wave.
// ---------------------------------------------------------------------------
__global__ __launch_bounds__(64)
void cscan_kernel(const int* __restrict__ gcnt, int* __restrict__ cstart,
                  int* __restrict__ gwptr, int* __restrict__ row_ptr) {
    const int t = threadIdx.x;
    const int b4 = t * 4;
    int c0 = (b4     < NCB) ? gcnt[b4]     : 0;
    int c1 = (b4 + 1 < NCB) ? gcnt[b4 + 1] : 0;
    int c2 = (b4 + 2 < NCB) ? gcnt[b4 + 2] : 0;
    int c3 = (b4 + 3 < NCB) ? gcnt[b4 + 3] : 0;
    const int s = c0 + c1 + c2 + c3;
    int inc = s;
    #pragma unroll
    for (int off = 1; off < 64; off <<= 1) {
        int u = __shfl_up(inc, off, 64);
        if (t >= off) inc += u;
    }
    int ex = inc - s;
    const int p0 = ex, p1 = ex + c0, p2 = p1 + c1, p3 = p2 + c2;
    if (b4     < NCB) { cstart[b4]     = p0; gwptr[b4]     = p0; }
    if (b4 + 1 < NCB) { cstart[b4 + 1] = p1; gwptr[b4 + 1] = p1; }
    if (b4 + 2 < NCB) { cstart[b4 + 2] = p2; gwptr[b4 + 2] = p2; }
    if (b4 + 3 < NCB) { cstart[b4 + 3] = p3; gwptr[b4 + 3] = p3; }
    if (t == 0) { cstart[NCB] = N_EDGES; row_ptr[N_NODES] = N_EDGES; }
}

// ---------------------------------------------------------------------------
// partA: bin EPA edges into 196 coarse buckets in LDS; wave-cooperative flush
// of contiguous runs (avg ~21 edges = 84B coalesced per run).
// Packed edge: dst(16b) << 16 | src(16b).
// ---------------------------------------------------------------------------
__global__ __launch_bounds__(256)
void partA_kernel(const int* __restrict__ src, const int* __restrict__ dst,
                  int* __restrict__ gwptr, unsigned int* __restrict__ gbuf) {
    __shared__ unsigned int pairs[EPA];      // 16 KB
    __shared__ int cnt[256], offs[256], wc[256];
    __shared__ int ws4[4];

    const int t = threadIdx.x;
    for (int i = t; i < 256; i += 256) cnt[i] = 0;
    __syncthreads();

    const int base = blockIdx.x * EPA;
    unsigned int ep[EPA / 256];
    int eb[EPA / 256];
    #pragma unroll
    for (int i = 0; i < EPA / 256; ++i) {
        int e = base + t + i * 256;
        if (e < N_EDGES) {
            unsigned int p = (((unsigned)dst[e]) << 16) | (unsigned)src[e];
            ep[i] = p;
            eb[i] = (int)(p >> 24);          // dst >> 8
            atomicAdd(&cnt[eb[i]], 1);
        } else {
            eb[i] = -1;
        }
    }
    __syncthreads();

    // exclusive scan of 256 bins: 4 bins/thread over threads 0..63 of wave 0,
    // plus cross-wave not needed (single wave covers 256 bins)
    if (t < 64) {
        const int b4 = t * 4;
        int c0 = cnt[b4], c1 = cnt[b4 + 1], c2 = cnt[b4 + 2], c3 = cnt[b4 + 3];
        const int s = c0 + c1 + c2 + c3;
        int inc = s;
        #pragma unroll
        for (int off = 1; off < 64; off <<= 1) {
            int u = __shfl_up(inc, off, 64);
            if (t >= off) inc += u;
        }
        int ex = inc - s;
        offs[b4] = ex;         wc[b4] = ex;
        offs[b4 + 1] = ex + c0; wc[b4 + 1] = ex + c0;
        offs[b4 + 2] = ex + c0 + c1; wc[b4 + 2] = ex + c0 + c1;
        offs[b4 + 3] = ex + c0 + c1 + c2; wc[b4 + 3] = ex + c0 + c1 + c2;
    }
    __syncthreads();

    #pragma unroll
    for (int i = 0; i < EPA / 256; ++i) {
        if (eb[i] >= 0) {
            int pos = atomicAdd(&wc[eb[i]], 1);
            pairs[pos] = ep[i];
        }
    }
    __syncthreads();

    // wave-cooperative flush: wave w handles buckets w, w+4, w+8, ...
    const int lane = t & 63;
    const int w = t >> 6;
    for (int b = w; b < NCB; b += 4) {
        int c = cnt[b];
        if (!c) continue;
        int gp = 0;
        if (lane == 0) gp = atomicAdd(&gwptr[b], c);
        gp = __shfl(gp, 0, 64);
        int o = offs[b];
        for (int i = lane; i < c; i += 64)
            gbuf[gp + i] = pairs[o + i];
    }
}

// ---------------------------------------------------------------------------
// partB: block per coarse bucket. Local counting sort by dst&255 entirely in
// LDS; fully-coalesced csr (ushort) + row_ptr writes.
// ---------------------------------------------------------------------------
__global__ __launch_bounds__(256)
void partB_kernel(const unsigned int* __restrict__ gbuf, const int* __restrict__ cstart,
                  unsigned short* __restrict__ csr16, int* __restrict__ row_ptr) {
    __shared__ unsigned int ep[MAXBE];   // 20 KB
    __shared__ unsigned int so[MAXBE];   // 20 KB
    __shared__ int cnt[256], offs[256], wc[256];

    const int t = threadIdx.x;
    const int b = blockIdx.x;
    cnt[t] = 0;
    __syncthreads();

    const int s0 = cstart[b], s1 = cstart[b + 1];
    const int ne = s1 - s0;

    for (int i = t; i < ne; i += 256) {
        unsigned int p = gbuf[s0 + i];
        if (i < MAXBE) ep[i] = p;
        atomicAdd(&cnt[(p >> 16) & 255], 1);
    }
    __syncthreads();

    if (t < 64) {
        const int b4 = t * 4;
        int c0 = cnt[b4], c1 = cnt[b4 + 1], c2 = cnt[b4 + 2], c3 = cnt[b4 + 3];
        const int s = c0 + c1 + c2 + c3;
        int inc = s;
        #pragma unroll
        for (int off = 1; off < 64; off <<= 1) {
            int u = __shfl_up(inc, off, 64);
            if (t >= off) inc += u;
        }
        int ex = inc - s;
        offs[b4] = ex;                    wc[b4] = ex;
        offs[b4 + 1] = ex + c0;           wc[b4 + 1] = ex + c0;
        offs[b4 + 2] = ex + c0 + c1;      wc[b4 + 2] = ex + c0 + c1;
        offs[b4 + 3] = ex + c0 + c1 + c2; wc[b4 + 3] = ex + c0 + c1 + c2;
    }
    __syncthreads();

    for (int i = t; i < ne; i += 256) {
        if (i < MAXBE) {
            unsigned int p = ep[i];
            int pos = atomicAdd(&wc[(p >> 16) & 255], 1);
            so[pos] = p;
        }
    }
    __syncthreads();

    for (int i = t; i < ne; i += 256)
        if (i < MAXBE) csr16[s0 + i] = (unsigned short)(so[i] & 0xFFFFu);

    int node = b * 256 + t;
    if (node < N_NODES) row_ptr[node] = s0 + offs[t];
}

// ---------------------------------------------------------------------------
// Gather: one wave per node, lane = feature dim. Reads bf16 h-half of xb for
// neighbors, writes bf16 mean (or own h) into the agg-half of xb.
// ---------------------------------------------------------------------------
__global__ __launch_bounds__(256)
void gather_kernel(const int* __restrict__ row_ptr,
                   const unsigned short* __restrict__ csr16,
                   unsigned short* __restrict__ xb) {
    int node = blockIdx.x * 4 + (threadIdx.x >> 6);
    if (node >= N_NODES) return;
    int d = threadIdx.x & 63;
    int start = row_ptr[node];
    int end = row_ptr[node + 1];
    int degc = end - start;
    float acc = 0.0f;
    int i = start;
    for (; i + 3 < end; i += 4) {
        int s0 = csr16[i], s1 = csr16[i + 1], s2 = csr16[i + 2], s3 = csr16[i + 3];
        float v0 = bf2f(xb[(size_t)s0 * 128 + d]);
        float v1 = bf2f(xb[(size_t)s1 * 128 + d]);
        float v2 = bf2f(xb[(size_t)s2 * 128 + d]);
        float v3 = bf2f(xb[(size_t)s3 * 128 + d]);
        acc += (v0 + v1) + (v2 + v3);
    }
    for (; i < end; ++i) acc += bf2f(xb[(size_t)csr16[i] * 128 + d]);
    unsigned short res;
    if (degc > 0) res = bf16_rne(acc / (float)degc);
    else          res = xb[(size_t)node * 128 + d];
    xb[(size_t)node * 128 + 64 + d] = res;
}

// ---------------------------------------------------------------------------
// MFMA MLP: block = 64 nodes, 4 waves. (unchanged from round 6)
// ---------------------------------------------------------------------------
__global__ __launch_bounds__(256)
void mlp_mfma_kernel(const unsigned short* __restrict__ xb,
                     const unsigned short* __restrict__ w1t,
                     const unsigned short* __restrict__ w2t,
                     const float* __restrict__ b1v,
                     const float* __restrict__ b2v,
                     float* __restrict__ out) {
    __shared__ unsigned short hid[64][264];

    const int tid = threadIdx.x;
    const int w   = tid >> 6;
    const int l   = tid & 63;
    const int l15 = l & 15;
    const int kg  = l >> 4;                 // 0..3
    const int node0 = blockIdx.x * 64;

    int arow[4];
    #pragma unroll
    for (int nt = 0; nt < 4; ++nt) {
        int r = node0 + nt * 16 + l15;
        arow[nt] = (r < N_NODES) ? r : (N_NODES - 1);
    }

    // ---- layer 1 ----
    f32x4 acc[4][4];   // [node-tile][j-tile]
    #pragma unroll
    for (int a = 0; a < 4; ++a)
        #pragma unroll
        for (int b = 0; b < 4; ++b) acc[a][b] = f32x4{0.f, 0.f, 0.f, 0.f};

    #pragma unroll
    for (int s = 0; s < 4; ++s) {
        const int kofs = s * 32 + kg * 8;
        bf16x8 a[4], b[4];
        #pragma unroll
        for (int nt = 0; nt < 4; ++nt)
            a[nt] = *(const bf16x8*)(xb + (size_t)arow[nt] * 128 + kofs);
        #pragma unroll
        for (int jt = 0; jt < 4; ++jt)
            b[jt] = *(const bf16x8*)(w1t + ((w * 4 + jt) * 16 + l15) * 128 + kofs);
        #pragma unroll
        for (int nt = 0; nt < 4; ++nt)
            #pragma unroll
            for (int jt = 0; jt < 4; ++jt)
                acc[nt][jt] = __builtin_amdgcn_mfma_f32_16x16x32_bf16(
                    a[nt], b[jt], acc[nt][jt], 0, 0, 0);
    }

    // ---- bias + exact GELU -> hid LDS ----
    #pragma unroll
    for (int jt = 0; jt < 4; ++jt) {
        const int jcol = (w * 4 + jt) * 16 + l15;
        float bias = b1v[jcol];
        #pragma unroll
        for (int nt = 0; nt < 4; ++nt) {
            #pragma unroll
            for (int r = 0; r < 4; ++r) {
                float v = acc[nt][jt][r] + bias;
                float g = 0.5f * v * (1.0f + erff(v * 0.70710678118654752440f));
                hid[nt * 16 + kg * 4 + r][jcol] = bf16_rne(g);
            }
        }
    }
    __syncthreads();

    // ---- layer 2: wave w -> d-tile w ----
    f32x4 acc2[4];
    #pragma unroll
    for (int a = 0; a < 4; ++a) acc2[a] = f32x4{0.f, 0.f, 0.f, 0.f};

    #pragma unroll
    for (int s = 0; s < 8; ++s) {
        const int kofs = s * 32 + kg * 8;
        bf16x8 bb = *(const bf16x8*)(w2t + (w * 16 + l15) * 256 + kofs);
        #pragma unroll
        for (int nt = 0; nt < 4; ++nt) {
            bf16x8 aa = *(const bf16x8*)&hid[nt * 16 + l15][kofs];
            acc2[nt] = __builtin_amdgcn_mfma_f32_16x16x32_bf16(aa, bb, acc2[nt], 0, 0, 0);
        }
    }

    float bias2 = b2v[w * 16 + l15];
    #pragma unroll
    for (int nt = 0; nt < 4; ++nt) {
        #pragma unroll
        for (int r = 0; r < 4; ++r) {
            int node = node0 + nt * 16 + kg * 4 + r;
            if (node < N_NODES)
                out[(size_t)node * DIM + w * 16 + l15] = acc2[nt][r] + bias2;
        }
    }
}

// ---------------------------------------------------------------------------
extern "C" void kernel_launch(void* const* d_in, const int* in_sizes, int n_in,
                              void* d_out, int out_size, void* d_ws, size_t ws_size,
                              hipStream_t stream) {
    const float* h  = (const float*)d_in[0];
    const int* eidx = (const int*)d_in[1];   // [2, N_EDGES]: src row then dst row
    const float* W1 = (const float*)d_in[2];
    const float* b1 = (const float*)d_in[3];
    const float* W2 = (const float*)d_in[4];
    const float* b2 = (const float*)d_in[5];
    float* out = (float*)d_out;

    const int* src = eidx;
    const int* dst = eidx + N_EDGES;

    // workspace layout
    unsigned short* xb    = (unsigned short*)d_ws;            // 6,400,000 ushort
    unsigned short* w1t   = xb + (size_t)N_NODES * 128;       // 32,768
    unsigned short* w2t   = w1t + 128 * 256;                  // 16,384
    unsigned int*   gbuf  = (unsigned int*)(w2t + 256 * 64);  // 800,000 uint
    unsigned short* csr16 = (unsigned short*)(gbuf + N_EDGES);// 800,000 ushort
    int* gcnt    = (int*)(csr16 + N_EDGES);                   // NCB
    int* cstart  = gcnt + NCB;                                // NCB+1
    int* gwptr   = cstart + NCB + 1;                          // NCB
    int* row_ptr = gwptr + NCB;                               // N_NODES+1

    hipMemsetAsync(gcnt, 0, (size_t)NCB * sizeof(int), stream);

    prep_kernel<<<(PREP_TOTAL + 255) / 256, 256, 0, stream>>>(h, W1, W2, xb, w1t, w2t);
    chist_kernel<<<ABLKS, 256, 0, stream>>>(dst, gcnt);
    cscan_kernel<<<1, 64, 0, stream>>>(gcnt, cstart, gwptr, row_ptr);
    partA_kernel<<<ABLKS, 256, 0, stream>>>(src, dst, gwptr, gbuf);
    partB_kernel<<<NCB, 256, 0, stream>>>(gbuf, cstart, csr16, row_ptr);
    {
        int grid = (N_NODES + 3) / 4;
        gather_kernel<<<grid, 256, 0, stream>>>(row_ptr, csr16, xb);
    }
    {
        int grid = (N_NODES + 63) / 64;
        mlp_mfma_kernel<<<grid, 256, 0, stream>>>(xb, w1t, w2t, b1, b2, out);
    }
}

// Round 9
// 123.024 us; speedup vs baseline: 3.7730x; 2.4591x over previous
//
#include <hip/hip_runtime.h>
#include <cstdint>

#define N_NODES 50000
#define N_EDGES 800000
#define DIM 64
#define HIDDEN 256

#define NCB 196                                  // coarse buckets (dst >> 8)
#define EPA 2048                                 // edges per partA/chist block
#define ABLKS ((N_EDGES + EPA - 1) / EPA)        // 391
#define MAXBE 5120                               // max edges per coarse bucket (mean 4081)

typedef __attribute__((ext_vector_type(8))) short bf16x8;
typedef __attribute__((ext_vector_type(4))) float f32x4;

__device__ __forceinline__ unsigned short bf16_rne(float f) {
    union { float f; uint32_t u; } cv; cv.f = f;
    uint32_t u = cv.u;
    u += 0x7FFFu + ((u >> 16) & 1u);
    return (unsigned short)(u >> 16);
}

__device__ __forceinline__ float bf2f(unsigned short us) {
    union { uint32_t u; float f; } cv; cv.u = ((uint32_t)us) << 16;
    return cv.f;
}

// ---------------------------------------------------------------------------
// Prep: bf16 conversions. xb h-half from h; w1t[n][k] (256x128); w2t[d][j] (64x256).
// ---------------------------------------------------------------------------
#define PREP_TOTAL (N_NODES * DIM + 128 * 256 + 256 * 64)
__global__ __launch_bounds__(256)
void prep_kernel(const float* __restrict__ h, const float* __restrict__ W1,
                 const float* __restrict__ W2, unsigned short* __restrict__ xb,
                 unsigned short* __restrict__ w1t, unsigned short* __restrict__ w2t) {
    int i = blockIdx.x * 256 + threadIdx.x;
    if (i < N_NODES * DIM) {
        int node = i >> 6, d = i & 63;
        xb[node * 128 + d] = bf16_rne(h[i]);
    } else if (i < N_NODES * DIM + 128 * 256) {
        int j = i - N_NODES * DIM;
        int k = j >> 8, n = j & 255;          // W1[k][n]
        w1t[n * 128 + k] = bf16_rne(W1[j]);
    } else if (i < PREP_TOTAL) {
        int j = i - N_NODES * DIM - 128 * 256;
        int jr = j >> 6, d = j & 63;          // W2[j][d]
        w2t[d * 256 + jr] = bf16_rne(W2[j]);
    }
}

// ---------------------------------------------------------------------------
// Coarse histogram over dst>>8: LDS bins, <=NCB global atomics per block.
// ---------------------------------------------------------------------------
__global__ __launch_bounds__(256)
void chist_kernel(const int* __restrict__ dst, int* __restrict__ gcnt) {
    __shared__ int lc[NCB];
    const int t = threadIdx.x;
    for (int i = t; i < NCB; i += 256) lc[i] = 0;
    __syncthreads();
    const int base = blockIdx.x * EPA;
    #pragma unroll
    for (int i = 0; i < EPA / 256; ++i) {
        int e = base + t + i * 256;
        if (e < N_EDGES) atomicAdd(&lc[((unsigned)dst[e]) >> 8], 1);
    }
    __syncthreads();
    for (int i = t; i < NCB; i += 256) {
        int c = lc[i];
        if (c) atomicAdd(&gcnt[i], c);
    }
}

// ---------------------------------------------------------------------------
// Scan of NCB coarse counts -> cstart (exclusive) + gwptr. Single wave.
// ---------------------------------------------------------------------------
__global__ __launch_bounds__(64)
void cscan_kernel(const int* __restrict__ gcnt, int* __restrict__ cstart,
                  int* __restrict__ gwptr, int* __restrict__ row_ptr) {
    const int t = threadIdx.x;
    const int b4 = t * 4;
    int c0 = (b4     < NCB) ? gcnt[b4]     : 0;
    int c1 = (b4 + 1 < NCB) ? gcnt[b4 + 1] : 0;
    int c2 = (b4 + 2 < NCB) ? gcnt[b4 + 2] : 0;
    int c3 = (b4 + 3 < NCB) ? gcnt[b4 + 3] : 0;
    const int s = c0 + c1 + c2 + c3;
    int inc = s;
    #pragma unroll
    for (int off = 1; off < 64; off <<= 1) {
        int u = __shfl_up(inc, off, 64);
        if (t >= off) inc += u;
    }
    int ex = inc - s;
    const int p0 = ex, p1 = ex + c0, p2 = p1 + c1, p3 = p2 + c2;
    if (b4     < NCB) { cstart[b4]     = p0; gwptr[b4]     = p0; }
    if (b4 + 1 < NCB) { cstart[b4 + 1] = p1; gwptr[b4 + 1] = p1; }
    if (b4 + 2 < NCB) { cstart[b4 + 2] = p2; gwptr[b4 + 2] = p2; }
    if (b4 + 3 < NCB) { cstart[b4 + 3] = p3; gwptr[b4 + 3] = p3; }
    if (t == 0) { cstart[NCB] = N_EDGES; row_ptr[N_NODES] = N_EDGES; }
}

// ---------------------------------------------------------------------------
// partA: bin EPA edges into NCB coarse buckets in LDS (two passes over global,
// no register staging), then fully-parallel coalesced flush.
// Packed edge: dst(16b) << 16 | src(16b).
// ---------------------------------------------------------------------------
__global__ __launch_bounds__(256)
void partA_kernel(const int* __restrict__ src, const int* __restrict__ dst,
                  int* __restrict__ gwptr, unsigned int* __restrict__ gbuf) {
    __shared__ unsigned int pairs[EPA];      // 8 KB
    __shared__ int cnt[NCB], offs[NCB], wc[NCB], gbase[NCB];

    const int t = threadIdx.x;
    for (int i = t; i < NCB; i += 256) cnt[i] = 0;
    __syncthreads();

    const int base = blockIdx.x * EPA;
    const int ne = (N_EDGES - base < EPA) ? (N_EDGES - base) : EPA;

    // pass 1: count
    #pragma unroll
    for (int i = 0; i < EPA / 256; ++i) {
        int e = t + i * 256;
        if (e < ne) atomicAdd(&cnt[((unsigned)dst[base + e]) >> 8], 1);
    }
    __syncthreads();

    // exclusive scan of NCB bins (wave 0, 4 bins/thread; 64*4=256 >= NCB)
    if (t < 64) {
        const int b4 = t * 4;
        int c0 = (b4     < NCB) ? cnt[b4]     : 0;
        int c1 = (b4 + 1 < NCB) ? cnt[b4 + 1] : 0;
        int c2 = (b4 + 2 < NCB) ? cnt[b4 + 2] : 0;
        int c3 = (b4 + 3 < NCB) ? cnt[b4 + 3] : 0;
        const int s = c0 + c1 + c2 + c3;
        int inc = s;
        #pragma unroll
        for (int off = 1; off < 64; off <<= 1) {
            int u = __shfl_up(inc, off, 64);
            if (t >= off) inc += u;
        }
        int ex = inc - s;
        if (b4     < NCB) { offs[b4]     = ex;               wc[b4]     = ex; }
        if (b4 + 1 < NCB) { offs[b4 + 1] = ex + c0;          wc[b4 + 1] = ex + c0; }
        if (b4 + 2 < NCB) { offs[b4 + 2] = ex + c0 + c1;     wc[b4 + 2] = ex + c0 + c1; }
        if (b4 + 3 < NCB) { offs[b4 + 3] = ex + c0 + c1 + c2; wc[b4 + 3] = ex + c0 + c1 + c2; }
    }
    __syncthreads();

    // pass 2: place into LDS (re-read src/dst from L2)
    #pragma unroll
    for (int i = 0; i < EPA / 256; ++i) {
        int e = t + i * 256;
        if (e < ne) {
            unsigned int d_ = (unsigned)dst[base + e];
            unsigned int p = (d_ << 16) | (unsigned)src[base + e];
            int pos = atomicAdd(&wc[d_ >> 8], 1);
            pairs[pos] = p;
        }
    }
    __syncthreads();

    // reserve global space: one atomic per bucket, all in parallel
    if (t < NCB) {
        int c = cnt[t];
        gbase[t] = c ? atomicAdd(&gwptr[t], c) : 0;
    }
    __syncthreads();

    // parallel coalesced flush: LDS is bucket-ordered -> sequential runs
    for (int p = t; p < ne; p += 256) {
        unsigned int pr = pairs[p];
        int b = (int)(pr >> 24);
        gbuf[gbase[b] + (p - offs[b])] = pr;
    }
}

// ---------------------------------------------------------------------------
// partB: block (1024 thr) per coarse bucket. LDS counting sort by dst&255;
// fully-coalesced csr16 + row_ptr writes.
// ---------------------------------------------------------------------------
__global__ __launch_bounds__(1024)
void partB_kernel(const unsigned int* __restrict__ gbuf, const int* __restrict__ cstart,
                  unsigned short* __restrict__ csr16, int* __restrict__ row_ptr) {
    __shared__ unsigned int ep[MAXBE];   // 20 KB
    __shared__ unsigned int so[MAXBE];   // 20 KB
    __shared__ int cnt[256], offs[256], wc[256];

    const int t = threadIdx.x;
    const int b = blockIdx.x;
    if (t < 256) cnt[t] = 0;
    __syncthreads();

    const int s0 = cstart[b], s1 = cstart[b + 1];
    const int ne = s1 - s0;

    for (int i = t; i < ne; i += 1024) {
        unsigned int p = gbuf[s0 + i];
        if (i < MAXBE) ep[i] = p;
        atomicAdd(&cnt[(p >> 16) & 255], 1);
    }
    __syncthreads();

    if (t < 64) {
        const int b4 = t * 4;
        int c0 = cnt[b4], c1 = cnt[b4 + 1], c2 = cnt[b4 + 2], c3 = cnt[b4 + 3];
        const int s = c0 + c1 + c2 + c3;
        int inc = s;
        #pragma unroll
        for (int off = 1; off < 64; off <<= 1) {
            int u = __shfl_up(inc, off, 64);
            if (t >= off) inc += u;
        }
        int ex = inc - s;
        offs[b4] = ex;                    wc[b4] = ex;
        offs[b4 + 1] = ex + c0;           wc[b4 + 1] = ex + c0;
        offs[b4 + 2] = ex + c0 + c1;      wc[b4 + 2] = ex + c0 + c1;
        offs[b4 + 3] = ex + c0 + c1 + c2; wc[b4 + 3] = ex + c0 + c1 + c2;
    }
    __syncthreads();

    for (int i = t; i < ne; i += 1024) {
        if (i < MAXBE) {
            unsigned int p = ep[i];
            int pos = atomicAdd(&wc[(p >> 16) & 255], 1);
            so[pos] = p;
        }
    }
    __syncthreads();

    for (int i = t; i < ne; i += 1024)
        if (i < MAXBE) csr16[s0 + i] = (unsigned short)(so[i] & 0xFFFFu);

    if (t < 256) {
        int node = b * 256 + t;
        if (node < N_NODES) row_ptr[node] = s0 + offs[t];
    }
}

// ---------------------------------------------------------------------------
// Gather: one wave per node, lane = feature dim. Reads bf16 h-half of xb for
// neighbors, writes bf16 mean (or own h) into the agg-half of xb.
// ---------------------------------------------------------------------------
__global__ __launch_bounds__(256)
void gather_kernel(const int* __restrict__ row_ptr,
                   const unsigned short* __restrict__ csr16,
                   unsigned short* __restrict__ xb) {
    int node = blockIdx.x * 4 + (threadIdx.x >> 6);
    if (node >= N_NODES) return;
    int d = threadIdx.x & 63;
    int start = row_ptr[node];
    int end = row_ptr[node + 1];
    int degc = end - start;
    float acc = 0.0f;
    int i = start;
    for (; i + 3 < end; i += 4) {
        int s0 = csr16[i], s1 = csr16[i + 1], s2 = csr16[i + 2], s3 = csr16[i + 3];
        float v0 = bf2f(xb[(size_t)s0 * 128 + d]);
        float v1 = bf2f(xb[(size_t)s1 * 128 + d]);
        float v2 = bf2f(xb[(size_t)s2 * 128 + d]);
        float v3 = bf2f(xb[(size_t)s3 * 128 + d]);
        acc += (v0 + v1) + (v2 + v3);
    }
    for (; i < end; ++i) acc += bf2f(xb[(size_t)csr16[i] * 128 + d]);
    unsigned short res;
    if (degc > 0) res = bf16_rne(acc / (float)degc);
    else          res = xb[(size_t)node * 128 + d];
    xb[(size_t)node * 128 + 64 + d] = res;
}

// ---------------------------------------------------------------------------
// MFMA MLP: block = 64 nodes, 4 waves.
// ---------------------------------------------------------------------------
__global__ __launch_bounds__(256)
void mlp_mfma_kernel(const unsigned short* __restrict__ xb,
                     const unsigned short* __restrict__ w1t,
                     const unsigned short* __restrict__ w2t,
                     const float* __restrict__ b1v,
                     const float* __restrict__ b2v,
                     float* __restrict__ out) {
    __shared__ unsigned short hid[64][264];

    const int tid = threadIdx.x;
    const int w   = tid >> 6;
    const int l   = tid & 63;
    const int l15 = l & 15;
    const int kg  = l >> 4;                 // 0..3
    const int node0 = blockIdx.x * 64;

    int arow[4];
    #pragma unroll
    for (int nt = 0; nt < 4; ++nt) {
        int r = node0 + nt * 16 + l15;
        arow[nt] = (r < N_NODES) ? r : (N_NODES - 1);
    }

    // ---- layer 1 ----
    f32x4 acc[4][4];   // [node-tile][j-tile]
    #pragma unroll
    for (int a = 0; a < 4; ++a)
        #pragma unroll
        for (int b = 0; b < 4; ++b) acc[a][b] = f32x4{0.f, 0.f, 0.f, 0.f};

    #pragma unroll
    for (int s = 0; s < 4; ++s) {
        const int kofs = s * 32 + kg * 8;
        bf16x8 a[4], b[4];
        #pragma unroll
        for (int nt = 0; nt < 4; ++nt)
            a[nt] = *(const bf16x8*)(xb + (size_t)arow[nt] * 128 + kofs);
        #pragma unroll
        for (int jt = 0; jt < 4; ++jt)
            b[jt] = *(const bf16x8*)(w1t + ((w * 4 + jt) * 16 + l15) * 128 + kofs);
        #pragma unroll
        for (int nt = 0; nt < 4; ++nt)
            #pragma unroll
            for (int jt = 0; jt < 4; ++jt)
                acc[nt][jt] = __builtin_amdgcn_mfma_f32_16x16x32_bf16(
                    a[nt], b[jt], acc[nt][jt], 0, 0, 0);
    }

    // ---- bias + exact GELU -> hid LDS ----
    #pragma unroll
    for (int jt = 0; jt < 4; ++jt) {
        const int jcol = (w * 4 + jt) * 16 + l15;
        float bias = b1v[jcol];
        #pragma unroll
        for (int nt = 0; nt < 4; ++nt) {
            #pragma unroll
            for (int r = 0; r < 4; ++r) {
                float v = acc[nt][jt][r] + bias;
                float g = 0.5f * v * (1.0f + erff(v * 0.70710678118654752440f));
                hid[nt * 16 + kg * 4 + r][jcol] = bf16_rne(g);
            }
        }
    }
    __syncthreads();

    // ---- layer 2: wave w -> d-tile w ----
    f32x4 acc2[4];
    #pragma unroll
    for (int a = 0; a < 4; ++a) acc2[a] = f32x4{0.f, 0.f, 0.f, 0.f};

    #pragma unroll
    for (int s = 0; s < 8; ++s) {
        const int kofs = s * 32 + kg * 8;
        bf16x8 bb = *(const bf16x8*)(w2t + (w * 16 + l15) * 256 + kofs);
        #pragma unroll
        for (int nt = 0; nt < 4; ++nt) {
            bf16x8 aa = *(const bf16x8*)&hid[nt * 16 + l15][kofs];
            acc2[nt] = __builtin_amdgcn_mfma_f32_16x16x32_bf16(aa, bb, acc2[nt], 0, 0, 0);
        }
    }

    float bias2 = b2v[w * 16 + l15];
    #pragma unroll
    for (int nt = 0; nt < 4; ++nt) {
        #pragma unroll
        for (int r = 0; r < 4; ++r) {
            int node = node0 + nt * 16 + kg * 4 + r;
            if (node < N_NODES)
                out[(size_t)node * DIM + w * 16 + l15] = acc2[nt][r] + bias2;
        }
    }
}

// ---------------------------------------------------------------------------
extern "C" void kernel_launch(void* const* d_in, const int* in_sizes, int n_in,
                              void* d_out, int out_size, void* d_ws, size_t ws_size,
                              hipStream_t stream) {
    const float* h  = (const float*)d_in[0];
    const int* eidx = (const int*)d_in[1];   // [2, N_EDGES]: src row then dst row
    const float* W1 = (const float*)d_in[2];
    const float* b1 = (const float*)d_in[3];
    const float* W2 = (const float*)d_in[4];
    const float* b2 = (const float*)d_in[5];
    float* out = (float*)d_out;

    const int* src = eidx;
    const int* dst = eidx + N_EDGES;

    // workspace layout
    unsigned short* xb    = (unsigned short*)d_ws;            // 6,400,000 ushort
    unsigned short* w1t   = xb + (size_t)N_NODES * 128;       // 32,768
    unsigned short* w2t   = w1t + 128 * 256;                  // 16,384
    unsigned int*   gbuf  = (unsigned int*)(w2t + 256 * 64);  // 800,000 uint
    unsigned short* csr16 = (unsigned short*)(gbuf + N_EDGES);// 800,000 ushort
    int* gcnt    = (int*)(csr16 + N_EDGES);                   // NCB
    int* cstart  = gcnt + NCB;                                // NCB+1
    int* gwptr   = cstart + NCB + 1;                          // NCB
    int* row_ptr = gwptr + NCB;                               // N_NODES+1

    hipMemsetAsync(gcnt, 0, (size_t)NCB * sizeof(int), stream);

    prep_kernel<<<(PREP_TOTAL + 255) / 256, 256, 0, stream>>>(h, W1, W2, xb, w1t, w2t);
    chist_kernel<<<ABLKS, 256, 0, stream>>>(dst, gcnt);
    cscan_kernel<<<1, 64, 0, stream>>>(gcnt, cstart, gwptr, row_ptr);
    partA_kernel<<<ABLKS, 256, 0, stream>>>(src, dst, gwptr, gbuf);
    partB_kernel<<<NCB, 1024, 0, stream>>>(gbuf, cstart, csr16, row_ptr);
    {
        int grid = (N_NODES + 3) / 4;
        gather_kernel<<<grid, 256, 0, stream>>>(row_ptr, csr16, xb);
    }
    {
        int grid = (N_NODES + 63) / 64;
        mlp_mfma_kernel<<<grid, 256, 0, stream>>>(xb, w1t, w2t, b1, b2, out);
    }
}

// Round 10
// 110.614 us; speedup vs baseline: 4.1963x; 1.1122x over previous
//
#include <hip/hip_runtime.h>
#include <cstdint>

#define N_NODES 50000
#define N_EDGES 800000
#define DIM 64
#define HIDDEN 256

#define NCB 196                                  // coarse buckets (dst >> 8)
#define EPA 2048                                 // edges per partA/chist block
#define ABLKS ((N_EDGES + EPA - 1) / EPA)        // 391
#define MAXBE 5120                               // max edges per coarse bucket (mean 4081)

typedef __attribute__((ext_vector_type(8))) short bf16x8;
typedef __attribute__((ext_vector_type(4))) float f32x4;

__device__ __forceinline__ unsigned short bf16_rne(float f) {
    union { float f; uint32_t u; } cv; cv.f = f;
    uint32_t u = cv.u;
    u += 0x7FFFu + ((u >> 16) & 1u);
    return (unsigned short)(u >> 16);
}

__device__ __forceinline__ float bf2f(unsigned short us) {
    union { uint32_t u; float f; } cv; cv.u = ((uint32_t)us) << 16;
    return cv.f;
}

// tanh-form GELU via v_exp_f32 (~10 VALU ops). Max |err| vs exact-erf GELU
// ~1e-3, far below the bf16 quantization already applied to hid.
__device__ __forceinline__ float gelu_f(float v) {
    float u = v * (0.7978845608028654f + 0.035677408136300125f * v * v);
    float e = __expf(fmaxf(fminf(2.0f * u, 80.0f), -80.0f));
    float th = (e - 1.0f) / (e + 1.0f);
    return 0.5f * v * (1.0f + th);
}

// ---------------------------------------------------------------------------
// Prep: bf16 conversions + zero gcnt (replaces the pathologically slow
// graph memset node). xb h-half; w1t[n][k] (256x128); w2t[d][j] (64x256).
// ---------------------------------------------------------------------------
#define PREP_TOTAL (N_NODES * DIM + 128 * 256 + 256 * 64)
__global__ __launch_bounds__(256)
void prep_kernel(const float* __restrict__ h, const float* __restrict__ W1,
                 const float* __restrict__ W2, unsigned short* __restrict__ xb,
                 unsigned short* __restrict__ w1t, unsigned short* __restrict__ w2t,
                 int* __restrict__ gcnt) {
    if (blockIdx.x == 0 && threadIdx.x < NCB) gcnt[threadIdx.x] = 0;
    int i = blockIdx.x * 256 + threadIdx.x;
    if (i < N_NODES * DIM) {
        int node = i >> 6, d = i & 63;
        xb[node * 128 + d] = bf16_rne(h[i]);
    } else if (i < N_NODES * DIM + 128 * 256) {
        int j = i - N_NODES * DIM;
        int k = j >> 8, n = j & 255;          // W1[k][n]
        w1t[n * 128 + k] = bf16_rne(W1[j]);
    } else if (i < PREP_TOTAL) {
        int j = i - N_NODES * DIM - 128 * 256;
        int jr = j >> 6, d = j & 63;          // W2[j][d]
        w2t[d * 256 + jr] = bf16_rne(W2[j]);
    }
}

// ---------------------------------------------------------------------------
// Coarse histogram over dst>>8: LDS bins, <=NCB global atomics per block.
// ---------------------------------------------------------------------------
__global__ __launch_bounds__(256)
void chist_kernel(const int* __restrict__ dst, int* __restrict__ gcnt) {
    __shared__ int lc[NCB];
    const int t = threadIdx.x;
    for (int i = t; i < NCB; i += 256) lc[i] = 0;
    __syncthreads();
    const int base = blockIdx.x * EPA;
    #pragma unroll
    for (int i = 0; i < EPA / 256; ++i) {
        int e = base + t + i * 256;
        if (e < N_EDGES) atomicAdd(&lc[((unsigned)dst[e]) >> 8], 1);
    }
    __syncthreads();
    for (int i = t; i < NCB; i += 256) {
        int c = lc[i];
        if (c) atomicAdd(&gcnt[i], c);
    }
}

// ---------------------------------------------------------------------------
// Scan of NCB coarse counts -> cstart (exclusive) + gwptr. Single wave.
// ---------------------------------------------------------------------------
__global__ __launch_bounds__(64)
void cscan_kernel(const int* __restrict__ gcnt, int* __restrict__ cstart,
                  int* __restrict__ gwptr, int* __restrict__ row_ptr) {
    const int t = threadIdx.x;
    const int b4 = t * 4;
    int c0 = (b4     < NCB) ? gcnt[b4]     : 0;
    int c1 = (b4 + 1 < NCB) ? gcnt[b4 + 1] : 0;
    int c2 = (b4 + 2 < NCB) ? gcnt[b4 + 2] : 0;
    int c3 = (b4 + 3 < NCB) ? gcnt[b4 + 3] : 0;
    const int s = c0 + c1 + c2 + c3;
    int inc = s;
    #pragma unroll
    for (int off = 1; off < 64; off <<= 1) {
        int u = __shfl_up(inc, off, 64);
        if (t >= off) inc += u;
    }
    int ex = inc - s;
    const int p0 = ex, p1 = ex + c0, p2 = p1 + c1, p3 = p2 + c2;
    if (b4     < NCB) { cstart[b4]     = p0; gwptr[b4]     = p0; }
    if (b4 + 1 < NCB) { cstart[b4 + 1] = p1; gwptr[b4 + 1] = p1; }
    if (b4 + 2 < NCB) { cstart[b4 + 2] = p2; gwptr[b4 + 2] = p2; }
    if (b4 + 3 < NCB) { cstart[b4 + 3] = p3; gwptr[b4 + 3] = p3; }
    if (t == 0) { cstart[NCB] = N_EDGES; row_ptr[N_NODES] = N_EDGES; }
}

// ---------------------------------------------------------------------------
// partA: bin EPA edges into NCB coarse buckets in LDS (two passes over global,
// no register staging), then fully-parallel coalesced flush.
// Packed edge: dst(16b) << 16 | src(16b).
// ---------------------------------------------------------------------------
__global__ __launch_bounds__(256)
void partA_kernel(const int* __restrict__ src, const int* __restrict__ dst,
                  int* __restrict__ gwptr, unsigned int* __restrict__ gbuf) {
    __shared__ unsigned int pairs[EPA];      // 8 KB
    __shared__ int cnt[NCB], offs[NCB], wc[NCB], gbase[NCB];

    const int t = threadIdx.x;
    for (int i = t; i < NCB; i += 256) cnt[i] = 0;
    __syncthreads();

    const int base = blockIdx.x * EPA;
    const int ne = (N_EDGES - base < EPA) ? (N_EDGES - base) : EPA;

    // pass 1: count
    #pragma unroll
    for (int i = 0; i < EPA / 256; ++i) {
        int e = t + i * 256;
        if (e < ne) atomicAdd(&cnt[((unsigned)dst[base + e]) >> 8], 1);
    }
    __syncthreads();

    // exclusive scan of NCB bins (wave 0, 4 bins/thread)
    if (t < 64) {
        const int b4 = t * 4;
        int c0 = (b4     < NCB) ? cnt[b4]     : 0;
        int c1 = (b4 + 1 < NCB) ? cnt[b4 + 1] : 0;
        int c2 = (b4 + 2 < NCB) ? cnt[b4 + 2] : 0;
        int c3 = (b4 + 3 < NCB) ? cnt[b4 + 3] : 0;
        const int s = c0 + c1 + c2 + c3;
        int inc = s;
        #pragma unroll
        for (int off = 1; off < 64; off <<= 1) {
            int u = __shfl_up(inc, off, 64);
            if (t >= off) inc += u;
        }
        int ex = inc - s;
        if (b4     < NCB) { offs[b4]     = ex;               wc[b4]     = ex; }
        if (b4 + 1 < NCB) { offs[b4 + 1] = ex + c0;          wc[b4 + 1] = ex + c0; }
        if (b4 + 2 < NCB) { offs[b4 + 2] = ex + c0 + c1;     wc[b4 + 2] = ex + c0 + c1; }
        if (b4 + 3 < NCB) { offs[b4 + 3] = ex + c0 + c1 + c2; wc[b4 + 3] = ex + c0 + c1 + c2; }
    }
    __syncthreads();

    // pass 2: place into LDS (re-read src/dst from L2)
    #pragma unroll
    for (int i = 0; i < EPA / 256; ++i) {
        int e = t + i * 256;
        if (e < ne) {
            unsigned int d_ = (unsigned)dst[base + e];
            unsigned int p = (d_ << 16) | (unsigned)src[base + e];
            int pos = atomicAdd(&wc[d_ >> 8], 1);
            pairs[pos] = p;
        }
    }
    __syncthreads();

    // reserve global space: one atomic per bucket, all in parallel
    if (t < NCB) {
        int c = cnt[t];
        gbase[t] = c ? atomicAdd(&gwptr[t], c) : 0;
    }
    __syncthreads();

    // parallel coalesced flush: LDS is bucket-ordered -> sequential runs
    for (int p = t; p < ne; p += 256) {
        unsigned int pr = pairs[p];
        int b = (int)(pr >> 24);
        gbuf[gbase[b] + (p - offs[b])] = pr;
    }
}

// ---------------------------------------------------------------------------
// partB: block (1024 thr) per coarse bucket. LDS counting sort by dst&255;
// fully-coalesced csr16 + row_ptr writes.
// ---------------------------------------------------------------------------
__global__ __launch_bounds__(1024)
void partB_kernel(const unsigned int* __restrict__ gbuf, const int* __restrict__ cstart,
                  unsigned short* __restrict__ csr16, int* __restrict__ row_ptr) {
    __shared__ unsigned int ep[MAXBE];   // 20 KB
    __shared__ unsigned int so[MAXBE];   // 20 KB
    __shared__ int cnt[256], offs[256], wc[256];

    const int t = threadIdx.x;
    const int b = blockIdx.x;
    if (t < 256) cnt[t] = 0;
    __syncthreads();

    const int s0 = cstart[b], s1 = cstart[b + 1];
    const int ne = s1 - s0;

    for (int i = t; i < ne; i += 1024) {
        unsigned int p = gbuf[s0 + i];
        if (i < MAXBE) ep[i] = p;
        atomicAdd(&cnt[(p >> 16) & 255], 1);
    }
    __syncthreads();

    if (t < 64) {
        const int b4 = t * 4;
        int c0 = cnt[b4], c1 = cnt[b4 + 1], c2 = cnt[b4 + 2], c3 = cnt[b4 + 3];
        const int s = c0 + c1 + c2 + c3;
        int inc = s;
        #pragma unroll
        for (int off = 1; off < 64; off <<= 1) {
            int u = __shfl_up(inc, off, 64);
            if (t >= off) inc += u;
        }
        int ex = inc - s;
        offs[b4] = ex;                    wc[b4] = ex;
        offs[b4 + 1] = ex + c0;           wc[b4 + 1] = ex + c0;
        offs[b4 + 2] = ex + c0 + c1;      wc[b4 + 2] = ex + c0 + c1;
        offs[b4 + 3] = ex + c0 + c1 + c2; wc[b4 + 3] = ex + c0 + c1 + c2;
    }
    __syncthreads();

    for (int i = t; i < ne; i += 1024) {
        if (i < MAXBE) {
            unsigned int p = ep[i];
            int pos = atomicAdd(&wc[(p >> 16) & 255], 1);
            so[pos] = p;
        }
    }
    __syncthreads();

    for (int i = t; i < ne; i += 1024)
        if (i < MAXBE) csr16[s0 + i] = (unsigned short)(so[i] & 0xFFFFu);

    if (t < 256) {
        int node = b * 256 + t;
        if (node < N_NODES) row_ptr[node] = s0 + offs[t];
    }
}

// ---------------------------------------------------------------------------
// Gather: one wave per node, lane = feature dim. Reads bf16 h-half of xb for
// neighbors, writes bf16 mean (or own h) into the agg-half of xb.
// ---------------------------------------------------------------------------
__global__ __launch_bounds__(256)
void gather_kernel(const int* __restrict__ row_ptr,
                   const unsigned short* __restrict__ csr16,
                   unsigned short* __restrict__ xb) {
    int node = blockIdx.x * 4 + (threadIdx.x >> 6);
    if (node >= N_NODES) return;
    int d = threadIdx.x & 63;
    int start = row_ptr[node];
    int end = row_ptr[node + 1];
    int degc = end - start;
    float acc = 0.0f;
    int i = start;
    for (; i + 3 < end; i += 4) {
        int s0 = csr16[i], s1 = csr16[i + 1], s2 = csr16[i + 2], s3 = csr16[i + 3];
        float v0 = bf2f(xb[(size_t)s0 * 128 + d]);
        float v1 = bf2f(xb[(size_t)s1 * 128 + d]);
        float v2 = bf2f(xb[(size_t)s2 * 128 + d]);
        float v3 = bf2f(xb[(size_t)s3 * 128 + d]);
        acc += (v0 + v1) + (v2 + v3);
    }
    for (; i < end; ++i) acc += bf2f(xb[(size_t)csr16[i] * 128 + d]);
    unsigned short res;
    if (degc > 0) res = bf16_rne(acc / (float)degc);
    else          res = xb[(size_t)node * 128 + d];
    xb[(size_t)node * 128 + 64 + d] = res;
}

// ---------------------------------------------------------------------------
// MFMA MLP: block = 32 nodes, 4 waves (1563 blocks -> ~6 blocks/CU).
// L1: wave w owns hidden slice [w*64, w*64+64) for all 32 nodes
//     (2 node-tiles x 4 j-tiles x 4 k-steps).
// GELU (fast tanh-form) -> hid LDS [32][264] bf16.
// L2: wave w owns output d-tile w (2 node-tiles x 8 k-steps).
// ---------------------------------------------------------------------------
__global__ __launch_bounds__(256, 4)
void mlp_mfma_kernel(const unsigned short* __restrict__ xb,
                     const unsigned short* __restrict__ w1t,
                     const unsigned short* __restrict__ w2t,
                     const float* __restrict__ b1v,
                     const float* __restrict__ b2v,
                     float* __restrict__ out) {
    __shared__ unsigned short hid[32][264];

    const int tid = threadIdx.x;
    const int w   = tid >> 6;
    const int l   = tid & 63;
    const int l15 = l & 15;
    const int kg  = l >> 4;                 // 0..3
    const int node0 = blockIdx.x * 32;

    int arow[2];
    #pragma unroll
    for (int nt = 0; nt < 2; ++nt) {
        int r = node0 + nt * 16 + l15;
        arow[nt] = (r < N_NODES) ? r : (N_NODES - 1);
    }

    // ---- layer 1 ----
    f32x4 acc[2][4];   // [node-tile][j-tile]
    #pragma unroll
    for (int a = 0; a < 2; ++a)
        #pragma unroll
        for (int b = 0; b < 4; ++b) acc[a][b] = f32x4{0.f, 0.f, 0.f, 0.f};

    #pragma unroll
    for (int s = 0; s < 4; ++s) {
        const int kofs = s * 32 + kg * 8;
        bf16x8 a[2], b[4];
        #pragma unroll
        for (int nt = 0; nt < 2; ++nt)
            a[nt] = *(const bf16x8*)(xb + (size_t)arow[nt] * 128 + kofs);
        #pragma unroll
        for (int jt = 0; jt < 4; ++jt)
            b[jt] = *(const bf16x8*)(w1t + ((w * 4 + jt) * 16 + l15) * 128 + kofs);
        #pragma unroll
        for (int nt = 0; nt < 2; ++nt)
            #pragma unroll
            for (int jt = 0; jt < 4; ++jt)
                acc[nt][jt] = __builtin_amdgcn_mfma_f32_16x16x32_bf16(
                    a[nt], b[jt], acc[nt][jt], 0, 0, 0);
    }

    // ---- bias + GELU -> hid LDS ----
    #pragma unroll
    for (int jt = 0; jt < 4; ++jt) {
        const int jcol = (w * 4 + jt) * 16 + l15;
        float bias = b1v[jcol];
        #pragma unroll
        for (int nt = 0; nt < 2; ++nt) {
            #pragma unroll
            for (int r = 0; r < 4; ++r) {
                float v = acc[nt][jt][r] + bias;
                hid[nt * 16 + kg * 4 + r][jcol] = bf16_rne(gelu_f(v));
            }
        }
    }
    __syncthreads();

    // ---- layer 2: wave w -> d-tile w ----
    f32x4 acc2[2];
    #pragma unroll
    for (int a = 0; a < 2; ++a) acc2[a] = f32x4{0.f, 0.f, 0.f, 0.f};

    #pragma unroll
    for (int s = 0; s < 8; ++s) {
        const int kofs = s * 32 + kg * 8;
        bf16x8 bb = *(const bf16x8*)(w2t + (w * 16 + l15) * 256 + kofs);
        #pragma unroll
        for (int nt = 0; nt < 2; ++nt) {
            bf16x8 aa = *(const bf16x8*)&hid[nt * 16 + l15][kofs];
            acc2[nt] = __builtin_amdgcn_mfma_f32_16x16x32_bf16(aa, bb, acc2[nt], 0, 0, 0);
        }
    }

    float bias2 = b2v[w * 16 + l15];
    #pragma unroll
    for (int nt = 0; nt < 2; ++nt) {
        #pragma unroll
        for (int r = 0; r < 4; ++r) {
            int node = node0 + nt * 16 + kg * 4 + r;
            if (node < N_NODES)
                out[(size_t)node * DIM + w * 16 + l15] = acc2[nt][r] + bias2;
        }
    }
}

// ---------------------------------------------------------------------------
extern "C" void kernel_launch(void* const* d_in, const int* in_sizes, int n_in,
                              void* d_out, int out_size, void* d_ws, size_t ws_size,
                              hipStream_t stream) {
    const float* h  = (const float*)d_in[0];
    const int* eidx = (const int*)d_in[1];   // [2, N_EDGES]: src row then dst row
    const float* W1 = (const float*)d_in[2];
    const float* b1 = (const float*)d_in[3];
    const float* W2 = (const float*)d_in[4];
    const float* b2 = (const float*)d_in[5];
    float* out = (float*)d_out;

    const int* src = eidx;
    const int* dst = eidx + N_EDGES;

    // workspace layout
    unsigned short* xb    = (unsigned short*)d_ws;            // 6,400,000 ushort
    unsigned short* w1t   = xb + (size_t)N_NODES * 128;       // 32,768
    unsigned short* w2t   = w1t + 128 * 256;                  // 16,384
    unsigned int*   gbuf  = (unsigned int*)(w2t + 256 * 64);  // 800,000 uint
    unsigned short* csr16 = (unsigned short*)(gbuf + N_EDGES);// 800,000 ushort
    int* gcnt    = (int*)(csr16 + N_EDGES);                   // NCB
    int* cstart  = gcnt + NCB;                                // NCB+1
    int* gwptr   = cstart + NCB + 1;                          // NCB
    int* row_ptr = gwptr + NCB;                               // N_NODES+1

    prep_kernel<<<(PREP_TOTAL + 255) / 256, 256, 0, stream>>>(h, W1, W2, xb, w1t, w2t, gcnt);
    chist_kernel<<<ABLKS, 256, 0, stream>>>(dst, gcnt);
    cscan_kernel<<<1, 64, 0, stream>>>(gcnt, cstart, gwptr, row_ptr);
    partA_kernel<<<ABLKS, 256, 0, stream>>>(src, dst, gwptr, gbuf);
    partB_kernel<<<NCB, 1024, 0, stream>>>(gbuf, cstart, csr16, row_ptr);
    {
        int grid = (N_NODES + 3) / 4;
        gather_kernel<<<grid, 256, 0, stream>>>(row_ptr, csr16, xb);
    }
    {
        int grid = (N_NODES + 31) / 32;
        mlp_mfma_kernel<<<grid, 256, 0, stream>>>(xb, w1t, w2t, b1, b2, out);
    }
}

// Round 11
// 91.791 us; speedup vs baseline: 5.0567x; 1.2051x over previous
//
#include <hip/hip_runtime.h>
#include <cstdint>

#define N_NODES 50000
#define N_EDGES 800000
#define DIM 64
#define HIDDEN 256

#define NCB 196                                  // coarse buckets (dst >> 8, 256 nodes each)
#define EPA 2048                                 // edges per partA block
#define ABLKS ((N_EDGES + EPA - 1) / EPA)        // 391
#define MAXBE 5120                               // bucket capacity (mean 4096, +16 sigma)

typedef __attribute__((ext_vector_type(8))) short bf16x8;
typedef __attribute__((ext_vector_type(4))) float f32x4;

__device__ __forceinline__ unsigned short bf16_rne(float f) {
    union { float f; uint32_t u; } cv; cv.f = f;
    uint32_t u = cv.u;
    u += 0x7FFFu + ((u >> 16) & 1u);
    return (unsigned short)(u >> 16);
}

__device__ __forceinline__ float bf2f(unsigned short us) {
    union { uint32_t u; float f; } cv; cv.u = ((uint32_t)us) << 16;
    return cv.f;
}

// tanh-form GELU via v_exp_f32; |err| vs exact erf-GELU ~1e-3 << bf16 quant.
__device__ __forceinline__ float gelu_f(float v) {
    float u = v * (0.7978845608028654f + 0.035677408136300125f * v * v);
    float e = __expf(fmaxf(fminf(2.0f * u, 80.0f), -80.0f));
    float th = (e - 1.0f) / (e + 1.0f);
    return 0.5f * v * (1.0f + th);
}

// ---------------------------------------------------------------------------
// Prep: bf16 conversions + zero bcnt. xb h-half; w1t[n][k]; w2t[d][j].
// ---------------------------------------------------------------------------
#define PREP_TOTAL (N_NODES * DIM + 128 * 256 + 256 * 64)
__global__ __launch_bounds__(256)
void prep_kernel(const float* __restrict__ h, const float* __restrict__ W1,
                 const float* __restrict__ W2, unsigned short* __restrict__ xb,
                 unsigned short* __restrict__ w1t, unsigned short* __restrict__ w2t,
                 int* __restrict__ bcnt) {
    if (blockIdx.x == 0 && threadIdx.x < NCB) bcnt[threadIdx.x] = 0;
    int i = blockIdx.x * 256 + threadIdx.x;
    if (i < N_NODES * DIM) {
        int node = i >> 6, d = i & 63;
        xb[node * 128 + d] = bf16_rne(h[i]);
    } else if (i < N_NODES * DIM + 128 * 256) {
        int j = i - N_NODES * DIM;
        int k = j >> 8, n = j & 255;          // W1[k][n]
        w1t[n * 128 + k] = bf16_rne(W1[j]);
    } else if (i < PREP_TOTAL) {
        int j = i - N_NODES * DIM - 128 * 256;
        int jr = j >> 6, d = j & 63;          // W2[j][d]
        w2t[d * 256 + jr] = bf16_rne(W2[j]);
    }
}

// ---------------------------------------------------------------------------
// partA: bin EPA edges into NCB buckets in LDS (two global passes), reserve
// fixed-capacity bucket space via bcnt, flush coalesced runs.
// Packed edge: dst(16b) << 16 | src(16b).
// ---------------------------------------------------------------------------
__global__ __launch_bounds__(256)
void partA_kernel(const int* __restrict__ src, const int* __restrict__ dst,
                  int* __restrict__ bcnt, unsigned int* __restrict__ gbuf) {
    __shared__ unsigned int pairs[EPA];      // 8 KB
    __shared__ int cnt[NCB], offs[NCB], wc[NCB], gbase[NCB];

    const int t = threadIdx.x;
    for (int i = t; i < NCB; i += 256) cnt[i] = 0;
    __syncthreads();

    const int base = blockIdx.x * EPA;
    const int ne = (N_EDGES - base < EPA) ? (N_EDGES - base) : EPA;

    // pass 1: count
    #pragma unroll
    for (int i = 0; i < EPA / 256; ++i) {
        int e = t + i * 256;
        if (e < ne) atomicAdd(&cnt[((unsigned)dst[base + e]) >> 8], 1);
    }
    __syncthreads();

    // exclusive scan of NCB bins (wave 0, 4 bins/thread)
    if (t < 64) {
        const int b4 = t * 4;
        int c0 = (b4     < NCB) ? cnt[b4]     : 0;
        int c1 = (b4 + 1 < NCB) ? cnt[b4 + 1] : 0;
        int c2 = (b4 + 2 < NCB) ? cnt[b4 + 2] : 0;
        int c3 = (b4 + 3 < NCB) ? cnt[b4 + 3] : 0;
        const int s = c0 + c1 + c2 + c3;
        int inc = s;
        #pragma unroll
        for (int off = 1; off < 64; off <<= 1) {
            int u = __shfl_up(inc, off, 64);
            if (t >= off) inc += u;
        }
        int ex = inc - s;
        if (b4     < NCB) { offs[b4]     = ex;                wc[b4]     = ex; }
        if (b4 + 1 < NCB) { offs[b4 + 1] = ex + c0;           wc[b4 + 1] = ex + c0; }
        if (b4 + 2 < NCB) { offs[b4 + 2] = ex + c0 + c1;      wc[b4 + 2] = ex + c0 + c1; }
        if (b4 + 3 < NCB) { offs[b4 + 3] = ex + c0 + c1 + c2; wc[b4 + 3] = ex + c0 + c1 + c2; }
    }
    __syncthreads();

    // pass 2: place into LDS (re-read src/dst from L2)
    #pragma unroll
    for (int i = 0; i < EPA / 256; ++i) {
        int e = t + i * 256;
        if (e < ne) {
            unsigned int d_ = (unsigned)dst[base + e];
            unsigned int p = (d_ << 16) | (unsigned)src[base + e];
            int pos = atomicAdd(&wc[d_ >> 8], 1);
            pairs[pos] = p;
        }
    }
    __syncthreads();

    // reserve bucket space: base = b*MAXBE + cursor
    if (t < NCB) {
        int c = cnt[t];
        gbase[t] = c ? (t * MAXBE + atomicAdd(&bcnt[t], c)) : 0;
    }
    __syncthreads();

    // coalesced flush (LDS bucket-ordered -> sequential runs), overflow-guarded
    for (int p = t; p < ne; p += 256) {
        unsigned int pr = pairs[p];
        int b = (int)(pr >> 24);
        int idx = gbase[b] + (p - offs[b]);
        if (idx < (b + 1) * MAXBE) gbuf[idx] = pr;
    }
}

// ---------------------------------------------------------------------------
// partB: block (1024 thr) per bucket. LDS counting sort by dst&255; coalesced
// csr16 writes; per-node [start,end) into rng (int2).
// ---------------------------------------------------------------------------
__global__ __launch_bounds__(1024)
void partB_kernel(const unsigned int* __restrict__ gbuf, const int* __restrict__ bcnt,
                  unsigned short* __restrict__ csr16, int2* __restrict__ rng) {
    __shared__ unsigned int ep[MAXBE];   // 20 KB
    __shared__ unsigned int so[MAXBE];   // 20 KB
    __shared__ int cnt[256], offs[256], wc[256];

    const int t = threadIdx.x;
    const int b = blockIdx.x;
    if (t < 256) cnt[t] = 0;
    __syncthreads();

    const int s0 = b * MAXBE;
    int ne = bcnt[b];
    if (ne > MAXBE) ne = MAXBE;

    for (int i = t; i < ne; i += 1024) {
        unsigned int p = gbuf[s0 + i];
        ep[i] = p;
        atomicAdd(&cnt[(p >> 16) & 255], 1);
    }
    __syncthreads();

    if (t < 64) {
        const int b4 = t * 4;
        int c0 = cnt[b4], c1 = cnt[b4 + 1], c2 = cnt[b4 + 2], c3 = cnt[b4 + 3];
        const int s = c0 + c1 + c2 + c3;
        int inc = s;
        #pragma unroll
        for (int off = 1; off < 64; off <<= 1) {
            int u = __shfl_up(inc, off, 64);
            if (t >= off) inc += u;
        }
        int ex = inc - s;
        offs[b4] = ex;                    wc[b4] = ex;
        offs[b4 + 1] = ex + c0;           wc[b4 + 1] = ex + c0;
        offs[b4 + 2] = ex + c0 + c1;      wc[b4 + 2] = ex + c0 + c1;
        offs[b4 + 3] = ex + c0 + c1 + c2; wc[b4 + 3] = ex + c0 + c1 + c2;
    }
    __syncthreads();

    for (int i = t; i < ne; i += 1024) {
        unsigned int p = ep[i];
        int pos = atomicAdd(&wc[(p >> 16) & 255], 1);
        so[pos] = p;
    }
    __syncthreads();

    for (int i = t; i < ne; i += 1024)
        csr16[s0 + i] = (unsigned short)(so[i] & 0xFFFFu);

    if (t < 256) {
        int node = b * 256 + t;
        if (node < N_NODES) {
            int st = s0 + offs[t];
            rng[node] = make_int2(st, st + cnt[t]);
        }
    }
}

// ---------------------------------------------------------------------------
// Gather: one wave per node, lane = feature dim, 8-deep load unroll.
// Reads bf16 h-half rows; writes bf16 mean (or own h) into agg-half of xb.
// ---------------------------------------------------------------------------
__global__ __launch_bounds__(256)
void gather_kernel(const int2* __restrict__ rng,
                   const unsigned short* __restrict__ csr16,
                   unsigned short* __restrict__ xb) {
    int node = blockIdx.x * 4 + (threadIdx.x >> 6);
    if (node >= N_NODES) return;
    int d = threadIdx.x & 63;
    int2 rg = rng[node];
    int start = rg.x, end = rg.y;
    int degc = end - start;
    float acc = 0.0f;
    int i = start;
    for (; i + 7 < end; i += 8) {
        int s0 = csr16[i],     s1 = csr16[i + 1], s2 = csr16[i + 2], s3 = csr16[i + 3];
        int s4 = csr16[i + 4], s5 = csr16[i + 5], s6 = csr16[i + 6], s7 = csr16[i + 7];
        float v0 = bf2f(xb[(size_t)s0 * 128 + d]);
        float v1 = bf2f(xb[(size_t)s1 * 128 + d]);
        float v2 = bf2f(xb[(size_t)s2 * 128 + d]);
        float v3 = bf2f(xb[(size_t)s3 * 128 + d]);
        float v4 = bf2f(xb[(size_t)s4 * 128 + d]);
        float v5 = bf2f(xb[(size_t)s5 * 128 + d]);
        float v6 = bf2f(xb[(size_t)s6 * 128 + d]);
        float v7 = bf2f(xb[(size_t)s7 * 128 + d]);
        acc += ((v0 + v1) + (v2 + v3)) + ((v4 + v5) + (v6 + v7));
    }
    for (; i + 3 < end; i += 4) {
        int s0 = csr16[i], s1 = csr16[i + 1], s2 = csr16[i + 2], s3 = csr16[i + 3];
        float v0 = bf2f(xb[(size_t)s0 * 128 + d]);
        float v1 = bf2f(xb[(size_t)s1 * 128 + d]);
        float v2 = bf2f(xb[(size_t)s2 * 128 + d]);
        float v3 = bf2f(xb[(size_t)s3 * 128 + d]);
        acc += (v0 + v1) + (v2 + v3);
    }
    for (; i < end; ++i) acc += bf2f(xb[(size_t)csr16[i] * 128 + d]);
    unsigned short res;
    if (degc > 0) res = bf16_rne(acc / (float)degc);
    else          res = xb[(size_t)node * 128 + d];
    xb[(size_t)node * 128 + 64 + d] = res;
}

// ---------------------------------------------------------------------------
// MFMA MLP: block = 32 nodes, 4 waves (1563 blocks).
// ---------------------------------------------------------------------------
__global__ __launch_bounds__(256, 4)
void mlp_mfma_kernel(const unsigned short* __restrict__ xb,
                     const unsigned short* __restrict__ w1t,
                     const unsigned short* __restrict__ w2t,
                     const float* __restrict__ b1v,
                     const float* __restrict__ b2v,
                     float* __restrict__ out) {
    __shared__ unsigned short hid[32][264];

    const int tid = threadIdx.x;
    const int w   = tid >> 6;
    const int l   = tid & 63;
    const int l15 = l & 15;
    const int kg  = l >> 4;                 // 0..3
    const int node0 = blockIdx.x * 32;

    int arow[2];
    #pragma unroll
    for (int nt = 0; nt < 2; ++nt) {
        int r = node0 + nt * 16 + l15;
        arow[nt] = (r < N_NODES) ? r : (N_NODES - 1);
    }

    // ---- layer 1 ----
    f32x4 acc[2][4];   // [node-tile][j-tile]
    #pragma unroll
    for (int a = 0; a < 2; ++a)
        #pragma unroll
        for (int b = 0; b < 4; ++b) acc[a][b] = f32x4{0.f, 0.f, 0.f, 0.f};

    #pragma unroll
    for (int s = 0; s < 4; ++s) {
        const int kofs = s * 32 + kg * 8;
        bf16x8 a[2], b[4];
        #pragma unroll
        for (int nt = 0; nt < 2; ++nt)
            a[nt] = *(const bf16x8*)(xb + (size_t)arow[nt] * 128 + kofs);
        #pragma unroll
        for (int jt = 0; jt < 4; ++jt)
            b[jt] = *(const bf16x8*)(w1t + ((w * 4 + jt) * 16 + l15) * 128 + kofs);
        #pragma unroll
        for (int nt = 0; nt < 2; ++nt)
            #pragma unroll
            for (int jt = 0; jt < 4; ++jt)
                acc[nt][jt] = __builtin_amdgcn_mfma_f32_16x16x32_bf16(
                    a[nt], b[jt], acc[nt][jt], 0, 0, 0);
    }

    // ---- bias + GELU -> hid LDS ----
    #pragma unroll
    for (int jt = 0; jt < 4; ++jt) {
        const int jcol = (w * 4 + jt) * 16 + l15;
        float bias = b1v[jcol];
        #pragma unroll
        for (int nt = 0; nt < 2; ++nt) {
            #pragma unroll
            for (int r = 0; r < 4; ++r) {
                float v = acc[nt][jt][r] + bias;
                hid[nt * 16 + kg * 4 + r][jcol] = bf16_rne(gelu_f(v));
            }
        }
    }
    __syncthreads();

    // ---- layer 2: wave w -> d-tile w ----
    f32x4 acc2[2];
    #pragma unroll
    for (int a = 0; a < 2; ++a) acc2[a] = f32x4{0.f, 0.f, 0.f, 0.f};

    #pragma unroll
    for (int s = 0; s < 8; ++s) {
        const int kofs = s * 32 + kg * 8;
        bf16x8 bb = *(const bf16x8*)(w2t + (w * 16 + l15) * 256 + kofs);
        #pragma unroll
        for (int nt = 0; nt < 2; ++nt) {
            bf16x8 aa = *(const bf16x8*)&hid[nt * 16 + l15][kofs];
            acc2[nt] = __builtin_amdgcn_mfma_f32_16x16x32_bf16(aa, bb, acc2[nt], 0, 0, 0);
        }
    }

    float bias2 = b2v[w * 16 + l15];
    #pragma unroll
    for (int nt = 0; nt < 2; ++nt) {
        #pragma unroll
        for (int r = 0; r < 4; ++r) {
            int node = node0 + nt * 16 + kg * 4 + r;
            if (node < N_NODES)
                out[(size_t)node * DIM + w * 16 + l15] = acc2[nt][r] + bias2;
        }
    }
}

// ---------------------------------------------------------------------------
extern "C" void kernel_launch(void* const* d_in, const int* in_sizes, int n_in,
                              void* d_out, int out_size, void* d_ws, size_t ws_size,
                              hipStream_t stream) {
    const float* h  = (const float*)d_in[0];
    const int* eidx = (const int*)d_in[1];   // [2, N_EDGES]: src row then dst row
    const float* W1 = (const float*)d_in[2];
    const float* b1 = (const float*)d_in[3];
    const float* W2 = (const float*)d_in[4];
    const float* b2 = (const float*)d_in[5];
    float* out = (float*)d_out;

    const int* src = eidx;
    const int* dst = eidx + N_EDGES;

    // workspace layout
    unsigned short* xb    = (unsigned short*)d_ws;               // 6,400,000 ushort
    unsigned short* w1t   = xb + (size_t)N_NODES * 128;          // 32,768
    unsigned short* w2t   = w1t + 128 * 256;                     // 16,384
    unsigned int*   gbuf  = (unsigned int*)(w2t + 256 * 64);     // NCB*MAXBE uint
    unsigned short* csr16 = (unsigned short*)(gbuf + NCB * MAXBE); // NCB*MAXBE ushort
    int*  bcnt = (int*)(csr16 + NCB * MAXBE);                    // NCB
    int2* rng  = (int2*)(bcnt + NCB + 2);                        // N_NODES (8B-aligned)

    prep_kernel<<<(PREP_TOTAL + 255) / 256, 256, 0, stream>>>(h, W1, W2, xb, w1t, w2t, bcnt);
    partA_kernel<<<ABLKS, 256, 0, stream>>>(src, dst, bcnt, gbuf);
    partB_kernel<<<NCB, 1024, 0, stream>>>(gbuf, bcnt, csr16, rng);
    {
        int grid = (N_NODES + 3) / 4;
        gather_kernel<<<grid, 256, 0, stream>>>(rng, csr16, xb);
    }
    {
        int grid = (N_NODES + 31) / 32;
        mlp_mfma_kernel<<<grid, 256, 0, stream>>>(xb, w1t, w2t, b1, b2, out);
    }
}